// Round 5
// baseline (3733.169 us; speedup 1.0000x reference)
//
#include <hip/hip_runtime.h>
#include <hip/hip_bf16.h>

// DGCNN-style KNN classifier. B=8, N=2048, K=10.
// Runtime dtype probe: inputs are either all-bf16 or all-fp32 (harness
// ambiguity); g_flag=1 -> bf16, 0 -> fp32. Output written in same dtype.
// Scratch in static __device__ globals; every byte read is written earlier
// in the same launch (graph-replay safe). No inf sentinels anywhere.

#define NEG 0.2f
#define FMAX 3.402823466e+38f

typedef __hip_bfloat16 bf16;

#define BB 8
#define NN 2048
#define BNTOT (BB * NN)

#define OFF_CAT ((size_t)0)
#define OFF_G (OFF_CAT + (size_t)BNTOT * 512)
#define OFF_NORMS (OFF_G + (size_t)BNTOT * 128)
#define OFF_PART (OFF_NORMS + BNTOT)
#define OFF_POOLED (OFF_PART + 8 * 1024 * 32)
#define OFF_H1 (OFF_POOLED + 8 * 1024)
#define OFF_H2 (OFF_H1 + 8 * 512)
#define WSF_TOTAL (OFF_H2 + 8 * 256)

__device__ float g_ws_f[WSF_TOTAL];          // ~43.1 MB
__device__ float g_D[(size_t)BNTOT * NN];    // 134 MB distance matrix
__device__ int g_ws_i[(size_t)BNTOT * 10];   // knn idx
__device__ int g_flag;                       // 1 = bf16 inputs, 0 = fp32

__device__ __forceinline__ float ldany(const void* p, size_t i, int isb) {
  if (isb) return __bfloat162float(((const bf16*)p)[i]);
  return ((const float*)p)[i];
}

// ---------------- dtype probe ----------------
__global__ void probe_kernel(const void* pts) {
  const unsigned* w = (const unsigned*)pts;
  int cnt = 0;
  for (int i = 0; i < 256; ++i) {
    unsigned e2 = (w[i] >> 7) & 0xFF;  // bf16-pair: low bf16's exponent field
    cnt += (e2 >= 110 && e2 <= 135);
  }
  g_flag = (cnt > 128) ? 1 : 0;
}

// ---------------- norms ----------------
template <bool XDYN>
__global__ void norms_kernel(const void* xraw, size_t xoff, int lda, int C, int BN) {
  const int isb = g_flag;
  float* norms = g_ws_f + OFF_NORMS;
  int row = blockIdx.x * (blockDim.x >> 6) + (threadIdx.x >> 6);
  int lane = threadIdx.x & 63;
  if (row >= BN) return;
  float s = 0.f;
  for (int c = lane; c < C; c += 64) {
    float v = XDYN ? ldany(xraw, (size_t)row * lda + c, isb)
                   : g_ws_f[xoff + (size_t)row * lda + c];
    s += v * v;
  }
#pragma unroll
  for (int off = 32; off > 0; off >>= 1) s += __shfl_down(s, off, 64);
  if (lane == 0) norms[row] = s;
}

// ---------------- distance tile: D[b][q][m] = |m|^2 - 2 q.m ----------------
template <bool XDYN, int C>
__global__ __launch_bounds__(256) void dist64_kernel(const void* xraw, size_t xoff,
                                                     int lda, int N) {
  const int isb = g_flag;
  constexpr int CC = (C <= 4) ? 4 : 64;
  constexpr int NCH = (C + CC - 1) / CC;
  __shared__ __align__(16) float qs[CC * 68];
  __shared__ __align__(16) float cs[CC * 68];
  const int tid = threadIdx.x;
  const int ty = tid >> 4, tx = tid & 15;
  const int b = blockIdx.z;
  const int q0 = blockIdx.x * 64;
  const int m0 = blockIdx.y * 64;
  const size_t rowbase = (size_t)b * N;
  const float* norms = g_ws_f + OFF_NORMS;

  float acc[4][4];
#pragma unroll
  for (int i = 0; i < 4; ++i)
#pragma unroll
    for (int j = 0; j < 4; ++j) acc[i][j] = 0.f;

  for (int ch = 0; ch < NCH; ++ch) {
    for (int i = tid; i < 64 * CC; i += 256) {
      int r = i / CC, c = i % CC; int cg = ch * CC + c;
      size_t gi = (rowbase + q0 + r) * lda + cg;
      qs[c * 68 + r] = (cg < C) ? (XDYN ? ldany(xraw, gi, isb) : g_ws_f[xoff + gi]) : 0.f;
    }
    for (int i = tid; i < 64 * CC; i += 256) {
      int r = i / CC, c = i % CC; int cg = ch * CC + c;
      size_t gi = (rowbase + m0 + r) * lda + cg;
      cs[c * 68 + r] = (cg < C) ? (XDYN ? ldany(xraw, gi, isb) : g_ws_f[xoff + gi]) : 0.f;
    }
    __syncthreads();
#pragma unroll 8
    for (int c = 0; c < CC; ++c) {
      const float4 a4 = *(const float4*)&qs[c * 68 + 4 * ty];
      const float4 b4 = *(const float4*)&cs[c * 68 + 4 * tx];
      acc[0][0] += a4.x * b4.x; acc[0][1] += a4.x * b4.y; acc[0][2] += a4.x * b4.z; acc[0][3] += a4.x * b4.w;
      acc[1][0] += a4.y * b4.x; acc[1][1] += a4.y * b4.y; acc[1][2] += a4.y * b4.z; acc[1][3] += a4.y * b4.w;
      acc[2][0] += a4.z * b4.x; acc[2][1] += a4.z * b4.y; acc[2][2] += a4.z * b4.z; acc[2][3] += a4.z * b4.w;
      acc[3][0] += a4.w * b4.x; acc[3][1] += a4.w * b4.y; acc[3][2] += a4.w * b4.z; acc[3][3] += a4.w * b4.w;
    }
    __syncthreads();
  }
  float nm[4];
#pragma unroll
  for (int j = 0; j < 4; ++j) nm[j] = norms[rowbase + m0 + 4 * tx + j];
#pragma unroll
  for (int i = 0; i < 4; ++i)
#pragma unroll
    for (int j = 0; j < 4; ++j)
      g_D[(rowbase + q0 + 4 * ty + i) * N + m0 + 4 * tx + j] = nm[j] - 2.f * acc[i][j];
}

// ---------------- per-thread top-10 scan ----------------
__global__ void topk_kernel(int N) {
  int row = blockIdx.x * blockDim.x + threadIdx.x;  // [0, BN)
  int q = row & (N - 1);
  const float* drow = g_D + (size_t)row * N;
  float bv[10]; int bi[10];
#pragma unroll
  for (int i = 0; i < 10; ++i) { bv[i] = FMAX; bi[i] = 0x7fffffff; }
  for (int m0 = 0; m0 < N; m0 += 4) {
    float4 d4 = *(const float4*)(drow + m0);
#pragma unroll
    for (int j = 0; j < 4; ++j) {
      int m = m0 + j;
      float d = (j == 0) ? d4.x : (j == 1) ? d4.y : (j == 2) ? d4.z : d4.w;
      if (m == q) continue;
      bool ins = (d < bv[9]) || (d == bv[9] && m < bi[9]);
      if (ins) {
        bool prev = true;
#pragma unroll
        for (int s = 9; s >= 1; --s) {
          bool sh = (d < bv[s - 1]) || (d == bv[s - 1] && m < bi[s - 1]);
          float nv = sh ? bv[s - 1] : (prev ? d : bv[s]);
          int ni = sh ? bi[s - 1] : (prev ? m : bi[s]);
          bv[s] = nv; bi[s] = ni; prev = sh;
        }
        if (prev) { bv[0] = d; bi[0] = m; }
      }
    }
  }
  int* ob = g_ws_i + (size_t)row * 10;
#pragma unroll
  for (int i = 0; i < 10; ++i) ob[i] = bi[i];
}

// ---------------- G[z][BN][64] = X @ W_half[o_base:+64]^T ----------------
template <bool XDYN, int C>
__global__ __launch_bounds__(256) void gmat64_kernel(const void* xraw, size_t xoff,
                                                     int lda, const void* W,
                                                     int o_base, int BN) {
  const int isb = g_flag;
  constexpr int CC = (C <= 4) ? 4 : 64;
  constexpr int NCH = (C + CC - 1) / CC;
  __shared__ __align__(16) float at[CC][68];
  __shared__ __align__(16) float wt[CC][68];
  const int tid = threadIdx.x;
  const int ty = tid >> 4, tx = tid & 15;
  const int r0 = blockIdx.x * 64;
  const int z = blockIdx.z;
  float* Gz = g_ws_f + OFF_G + (size_t)z * BN * 64;
  float acc[4][4];
#pragma unroll
  for (int i = 0; i < 4; ++i)
#pragma unroll
    for (int j = 0; j < 4; ++j) acc[i][j] = 0.f;

  for (int ch = 0; ch < NCH; ++ch) {
    int c0 = ch * CC;
    for (int i = tid; i < 64 * CC; i += 256) {
      int r = i / CC, c = i % CC; int cg = c0 + c;
      size_t gi = (size_t)(r0 + r) * lda + cg;
      at[c][r] = (cg < C) ? (XDYN ? ldany(xraw, gi, isb) : g_ws_f[xoff + gi]) : 0.f;
    }
    for (int i = tid; i < 64 * CC; i += 256) {
      int r = i / CC, c = i % CC; int cg = c0 + c;
      // W row (o_base+r), column z*C + cg, row stride 2C
      size_t wi = (size_t)(o_base + r) * (2 * C) + (size_t)z * C + cg;
      wt[c][r] = (cg < C) ? ldany(W, wi, isb) : 0.f;
    }
    __syncthreads();
#pragma unroll 8
    for (int c = 0; c < CC; ++c) {
      const float4 a4 = *(const float4*)&at[c][4 * ty];
      const float4 w4 = *(const float4*)&wt[c][4 * tx];
      acc[0][0] += a4.x * w4.x; acc[0][1] += a4.x * w4.y; acc[0][2] += a4.x * w4.z; acc[0][3] += a4.x * w4.w;
      acc[1][0] += a4.y * w4.x; acc[1][1] += a4.y * w4.y; acc[1][2] += a4.y * w4.z; acc[1][3] += a4.y * w4.w;
      acc[2][0] += a4.z * w4.x; acc[2][1] += a4.z * w4.y; acc[2][2] += a4.z * w4.z; acc[2][3] += a4.z * w4.w;
      acc[3][0] += a4.w * w4.x; acc[3][1] += a4.w * w4.y; acc[3][2] += a4.w * w4.z; acc[3][3] += a4.w * w4.w;
    }
    __syncthreads();
  }
#pragma unroll
  for (int i = 0; i < 4; ++i)
#pragma unroll
    for (int j = 0; j < 4; ++j)
      Gz[(size_t)(r0 + 4 * ty + i) * 64 + 4 * tx + j] = acc[i][j];
}

// ---------------- edge-conv epilogue (64-out chunk) ----------------
__global__ void edge_epi64(const void* s, const void* t, int coff,
                           size_t outoff, int BN, int N) {
  const int isb = g_flag;
  int tid = threadIdx.x;
  int p = tid >> 6, o = tid & 63;
  int row = blockIdx.x * 4 + p;
  const float* G1 = g_ws_f + OFF_G;
  const float* G2 = G1 + (size_t)BN * 64;
  float* out = g_ws_f + outoff;
  int b = row / N;
  const int* id = g_ws_i + (size_t)row * 10;
  float g1n = G1[(size_t)row * 64 + o];
  float base = G2[(size_t)row * 64 + o] - g1n;
  float sv = ldany(s, coff + o, isb), tv = ldany(t, coff + o, isb);
  float mx = -FMAX;
#pragma unroll
  for (int k = 0; k < 10; ++k) {
    int m = id[k];
    m = (m < 0) ? 0 : ((m >= N) ? N - 1 : m);
    float h = sv * (G1[((size_t)b * N + m) * 64 + o] + base) + tv;
    h = (h >= 0.f) ? h : NEG * h;
    mx = fmaxf(mx, h);
  }
  out[(size_t)row * 512 + o] = mx;
}

// ---------------- W5 matmul + lrelu + partial max over n ----------------
__global__ __launch_bounds__(256) void w5max_kernel(const void* W5, const void* s5,
                                                    const void* t5, int N) {
  const int isb = g_flag;
  const float* cat = g_ws_f + OFF_CAT;
  float* part = g_ws_f + OFF_PART;
  __shared__ __align__(16) float at[64][68];
  __shared__ __align__(16) float wt[64][68];
  __shared__ __align__(16) float red[64][17];
  const int tid = threadIdx.x;
  const int ty = tid >> 4, tx = tid & 15;
  const int b = blockIdx.z;
  const int o0 = blockIdx.y * 64;
  const int n0 = blockIdx.x * 64;
  const size_t rowb = (size_t)b * N + n0;
  float acc[4][4];
#pragma unroll
  for (int i = 0; i < 4; ++i)
#pragma unroll
    for (int j = 0; j < 4; ++j) acc[i][j] = 0.f;

  for (int c0 = 0; c0 < 512; c0 += 64) {
    for (int i = tid; i < 64 * 64; i += 256) {
      int r = i >> 6, c = i & 63;
      at[c][r] = cat[(rowb + r) * 512 + c0 + c];
    }
    for (int i = tid; i < 64 * 64; i += 256) {
      int r = i >> 6, c = i & 63;
      wt[c][r] = ldany(W5, (size_t)(o0 + r) * 512 + c0 + c, isb);
    }
    __syncthreads();
#pragma unroll 8
    for (int c = 0; c < 64; ++c) {
      const float4 w4 = *(const float4*)&wt[c][4 * ty];
      const float4 a4 = *(const float4*)&at[c][4 * tx];
      acc[0][0] += w4.x * a4.x; acc[0][1] += w4.x * a4.y; acc[0][2] += w4.x * a4.z; acc[0][3] += w4.x * a4.w;
      acc[1][0] += w4.y * a4.x; acc[1][1] += w4.y * a4.y; acc[1][2] += w4.y * a4.z; acc[1][3] += w4.y * a4.w;
      acc[2][0] += w4.z * a4.x; acc[2][1] += w4.z * a4.y; acc[2][2] += w4.z * a4.z; acc[2][3] += w4.z * a4.w;
      acc[3][0] += w4.w * a4.x; acc[3][1] += w4.w * a4.y; acc[3][2] += w4.w * a4.z; acc[3][3] += w4.w * a4.w;
    }
    __syncthreads();
  }
#pragma unroll
  for (int i = 0; i < 4; ++i) {
    int o = o0 + 4 * ty + i;
    float sv = ldany(s5, o, isb), tv = ldany(t5, o, isb);
    float m = -FMAX;
#pragma unroll
    for (int j = 0; j < 4; ++j) {
      float h = sv * acc[i][j] + tv;
      h = (h >= 0.f) ? h : NEG * h;
      m = fmaxf(m, h);
    }
    red[4 * ty + i][tx] = m;
  }
  __syncthreads();
  if (tid < 64) {
    float m = -FMAX;
#pragma unroll
    for (int x = 0; x < 16; ++x) m = fmaxf(m, red[tid][x]);
    part[((size_t)b * 1024 + o0 + tid) * 32 + blockIdx.x] = m;
  }
}

__global__ void poolred_kernel() {
  const float* part = g_ws_f + OFF_PART;
  float* pooled = g_ws_f + OFF_POOLED;
  int i = blockIdx.x * blockDim.x + threadIdx.x;
  if (i >= 8 * 1024) return;
  const float* p = part + (size_t)i * 32;
  float m = -FMAX;
#pragma unroll
  for (int j = 0; j < 32; ++j) m = fmaxf(m, p[j]);
  pooled[i] = m;
}

// ---------------- FC: one wave per output ----------------
__global__ void fc_kernel(size_t inoff, const void* W, const void* bias,
                          const void* s, const void* t, size_t outoff, int has_out,
                          void* OUTB, int Bb, int IC, int OC, int act) {
  const int isb = g_flag;
  const float* IN = g_ws_f + inoff;
  int gw = (blockIdx.x * blockDim.x + threadIdx.x) >> 6;
  int lane = threadIdx.x & 63;
  if (gw >= Bb * OC) return;
  int b = gw / OC, o = gw % OC;
  const float* in = IN + (size_t)b * IC;
  float acc = 0.f;
  for (int c = lane; c < IC; c += 64) acc += in[c] * ldany(W, (size_t)o * IC + c, isb);
#pragma unroll
  for (int off = 32; off > 0; off >>= 1) acc += __shfl_down(acc, off, 64);
  if (lane == 0) {
    float h = acc;
    if (bias) h += ldany(bias, o, isb);
    if (s) h = h * ldany(s, o, isb) + ldany(t, o, isb);
    if (act) h = (h >= 0.f) ? h : NEG * h;
    if (has_out) g_ws_f[outoff + (size_t)b * OC + o] = h;
    if (OUTB) {
      if (isb) ((bf16*)OUTB)[(size_t)b * OC + o] = __float2bfloat16(h);
      else ((float*)OUTB)[(size_t)b * OC + o] = h;
    }
  }
}

extern "C" void kernel_launch(void* const* d_in, const int* in_sizes, int n_in,
                              void* d_out, int out_size, void* d_ws, size_t ws_size,
                              hipStream_t stream) {
  const int B = 8, N = 2048, BN = B * N;
  const void* points = d_in[0];
  const void *W1 = d_in[1], *s1 = d_in[2], *t1 = d_in[3];
  const void *W2 = d_in[4], *s2 = d_in[5], *t2 = d_in[6];
  const void *W3 = d_in[7], *s3 = d_in[8], *t3 = d_in[9];
  const void *W4 = d_in[10], *s4 = d_in[11], *t4 = d_in[12];
  const void *W5 = d_in[13], *s5 = d_in[14], *t5 = d_in[15];
  const void *Wf1 = d_in[16], *sf1 = d_in[17], *tf1 = d_in[18];
  const void *Wf2 = d_in[19], *bf2 = d_in[20], *sf2 = d_in[21], *tf2 = d_in[22];
  const void *Wf3 = d_in[23], *bf3 = d_in[24];

  probe_kernel<<<1, 1, 0, stream>>>(points);

  // ---- layer 1: points (C=3) -> cat[:, 0:64)
  norms_kernel<true><<<BN / 4, 256, 0, stream>>>(points, 0, 3, 3, BN);
  dist64_kernel<true, 3><<<dim3(N / 64, N / 64, B), 256, 0, stream>>>(points, 0, 3, N);
  topk_kernel<<<BN / 256, 256, 0, stream>>>(N);
  gmat64_kernel<true, 3><<<dim3(BN / 64, 1, 2), 256, 0, stream>>>(points, 0, 3, W1, 0, BN);
  edge_epi64<<<BN / 4, 256, 0, stream>>>(s1, t1, 0, OFF_CAT + 0, BN, N);
  // ---- layer 2: cat[:,0:64) (C=64) -> cat[:, 64:128)
  norms_kernel<false><<<BN / 4, 256, 0, stream>>>(nullptr, OFF_CAT + 0, 512, 64, BN);
  dist64_kernel<false, 64><<<dim3(N / 64, N / 64, B), 256, 0, stream>>>(nullptr, OFF_CAT + 0, 512, N);
  topk_kernel<<<BN / 256, 256, 0, stream>>>(N);
  gmat64_kernel<false, 64><<<dim3(BN / 64, 1, 2), 256, 0, stream>>>(nullptr, OFF_CAT + 0, 512, W2, 0, BN);
  edge_epi64<<<BN / 4, 256, 0, stream>>>(s2, t2, 0, OFF_CAT + 64, BN, N);
  // ---- layer 3: cat[:,64:128) (C=64) -> cat[:, 128:256)
  norms_kernel<false><<<BN / 4, 256, 0, stream>>>(nullptr, OFF_CAT + 64, 512, 64, BN);
  dist64_kernel<false, 64><<<dim3(N / 64, N / 64, B), 256, 0, stream>>>(nullptr, OFF_CAT + 64, 512, N);
  topk_kernel<<<BN / 256, 256, 0, stream>>>(N);
  for (int c = 0; c < 2; ++c) {
    gmat64_kernel<false, 64><<<dim3(BN / 64, 1, 2), 256, 0, stream>>>(nullptr, OFF_CAT + 64, 512, W3, c * 64, BN);
    edge_epi64<<<BN / 4, 256, 0, stream>>>(s3, t3, c * 64, OFF_CAT + 128 + c * 64, BN, N);
  }
  // ---- layer 4: cat[:,128:256) (C=128) -> cat[:, 256:512)
  norms_kernel<false><<<BN / 4, 256, 0, stream>>>(nullptr, OFF_CAT + 128, 512, 128, BN);
  dist64_kernel<false, 128><<<dim3(N / 64, N / 64, B), 256, 0, stream>>>(nullptr, OFF_CAT + 128, 512, N);
  topk_kernel<<<BN / 256, 256, 0, stream>>>(N);
  for (int c = 0; c < 4; ++c) {
    gmat64_kernel<false, 128><<<dim3(BN / 64, 1, 2), 256, 0, stream>>>(nullptr, OFF_CAT + 128, 512, W4, c * 64, BN);
    edge_epi64<<<BN / 4, 256, 0, stream>>>(s4, t4, c * 64, OFF_CAT + 256 + c * 64, BN, N);
  }
  // ---- W5 + global max pool
  w5max_kernel<<<dim3(32, 16, 8), 256, 0, stream>>>(W5, s5, t5, N);
  poolred_kernel<<<32, 256, 0, stream>>>();
  // ---- FC head
  fc_kernel<<<(8 * 512 * 64) / 256, 256, 0, stream>>>(OFF_POOLED, Wf1, nullptr, sf1, tf1, OFF_H1, 1, nullptr, 8, 1024, 512, 1);
  fc_kernel<<<(8 * 256 * 64) / 256, 256, 0, stream>>>(OFF_H1, Wf2, bf2, sf2, tf2, OFF_H2, 1, nullptr, 8, 512, 256, 1);
  fc_kernel<<<6, 256, 0, stream>>>(OFF_H2, Wf3, bf3, nullptr, nullptr, 0, 0, d_out, 8, 256, 3, 0);
}

// Round 6
// 1238.855 us; speedup vs baseline: 3.0134x; 3.0134x over previous
//
#include <hip/hip_runtime.h>
#include <hip/hip_bf16.h>

// DGCNN-style KNN classifier. B=8, N=2048, K=10.
// Runtime dtype probe: inputs are either all-bf16 or all-fp32 (harness
// ambiguity); g_flag=1 -> bf16, 0 -> fp32. Output written in same dtype.
// Scratch in static __device__ globals; every byte read is written earlier
// in the same launch (graph-replay safe). No inf sentinels anywhere.
//
// R5->R6: topk_kernel was 77% of runtime at 2.8% occupancy (1 thread/row,
// latency-bound). Now 1 wave/row with 10 rounds of wave-wide lexicographic
// (dist,idx) min-selection. Same selection semantics (ties -> lower index).

#define NEG 0.2f
#define FMAX 3.402823466e+38f

typedef __hip_bfloat16 bf16;

#define BB 8
#define NN 2048
#define BNTOT (BB * NN)

#define OFF_CAT ((size_t)0)
#define OFF_G (OFF_CAT + (size_t)BNTOT * 512)
#define OFF_NORMS (OFF_G + (size_t)BNTOT * 128)
#define OFF_PART (OFF_NORMS + BNTOT)
#define OFF_POOLED (OFF_PART + 8 * 1024 * 32)
#define OFF_H1 (OFF_POOLED + 8 * 1024)
#define OFF_H2 (OFF_H1 + 8 * 512)
#define WSF_TOTAL (OFF_H2 + 8 * 256)

__device__ float g_ws_f[WSF_TOTAL];          // ~43.1 MB
__device__ float g_D[(size_t)BNTOT * NN];    // 134 MB distance matrix
__device__ int g_ws_i[(size_t)BNTOT * 10];   // knn idx
__device__ int g_flag;                       // 1 = bf16 inputs, 0 = fp32

__device__ __forceinline__ float ldany(const void* p, size_t i, int isb) {
  if (isb) return __bfloat162float(((const bf16*)p)[i]);
  return ((const float*)p)[i];
}

// ---------------- dtype probe ----------------
__global__ void probe_kernel(const void* pts) {
  const unsigned* w = (const unsigned*)pts;
  int cnt = 0;
  for (int i = 0; i < 256; ++i) {
    unsigned e2 = (w[i] >> 7) & 0xFF;  // bf16-pair: low bf16's exponent field
    cnt += (e2 >= 110 && e2 <= 135);
  }
  g_flag = (cnt > 128) ? 1 : 0;
}

// ---------------- norms ----------------
template <bool XDYN>
__global__ void norms_kernel(const void* xraw, size_t xoff, int lda, int C, int BN) {
  const int isb = g_flag;
  float* norms = g_ws_f + OFF_NORMS;
  int row = blockIdx.x * (blockDim.x >> 6) + (threadIdx.x >> 6);
  int lane = threadIdx.x & 63;
  if (row >= BN) return;
  float s = 0.f;
  for (int c = lane; c < C; c += 64) {
    float v = XDYN ? ldany(xraw, (size_t)row * lda + c, isb)
                   : g_ws_f[xoff + (size_t)row * lda + c];
    s += v * v;
  }
#pragma unroll
  for (int off = 32; off > 0; off >>= 1) s += __shfl_down(s, off, 64);
  if (lane == 0) norms[row] = s;
}

// ---------------- distance tile: D[b][q][m] = |m|^2 - 2 q.m ----------------
template <bool XDYN, int C>
__global__ __launch_bounds__(256) void dist64_kernel(const void* xraw, size_t xoff,
                                                     int lda, int N) {
  const int isb = g_flag;
  constexpr int CC = (C <= 4) ? 4 : 64;
  constexpr int NCH = (C + CC - 1) / CC;
  __shared__ __align__(16) float qs[CC * 68];
  __shared__ __align__(16) float cs[CC * 68];
  const int tid = threadIdx.x;
  const int ty = tid >> 4, tx = tid & 15;
  const int b = blockIdx.z;
  const int q0 = blockIdx.x * 64;
  const int m0 = blockIdx.y * 64;
  const size_t rowbase = (size_t)b * N;
  const float* norms = g_ws_f + OFF_NORMS;

  float acc[4][4];
#pragma unroll
  for (int i = 0; i < 4; ++i)
#pragma unroll
    for (int j = 0; j < 4; ++j) acc[i][j] = 0.f;

  for (int ch = 0; ch < NCH; ++ch) {
    for (int i = tid; i < 64 * CC; i += 256) {
      int r = i / CC, c = i % CC; int cg = ch * CC + c;
      size_t gi = (rowbase + q0 + r) * lda + cg;
      qs[c * 68 + r] = (cg < C) ? (XDYN ? ldany(xraw, gi, isb) : g_ws_f[xoff + gi]) : 0.f;
    }
    for (int i = tid; i < 64 * CC; i += 256) {
      int r = i / CC, c = i % CC; int cg = ch * CC + c;
      size_t gi = (rowbase + m0 + r) * lda + cg;
      cs[c * 68 + r] = (cg < C) ? (XDYN ? ldany(xraw, gi, isb) : g_ws_f[xoff + gi]) : 0.f;
    }
    __syncthreads();
#pragma unroll 8
    for (int c = 0; c < CC; ++c) {
      const float4 a4 = *(const float4*)&qs[c * 68 + 4 * ty];
      const float4 b4 = *(const float4*)&cs[c * 68 + 4 * tx];
      acc[0][0] += a4.x * b4.x; acc[0][1] += a4.x * b4.y; acc[0][2] += a4.x * b4.z; acc[0][3] += a4.x * b4.w;
      acc[1][0] += a4.y * b4.x; acc[1][1] += a4.y * b4.y; acc[1][2] += a4.y * b4.z; acc[1][3] += a4.y * b4.w;
      acc[2][0] += a4.z * b4.x; acc[2][1] += a4.z * b4.y; acc[2][2] += a4.z * b4.z; acc[2][3] += a4.z * b4.w;
      acc[3][0] += a4.w * b4.x; acc[3][1] += a4.w * b4.y; acc[3][2] += a4.w * b4.z; acc[3][3] += a4.w * b4.w;
    }
    __syncthreads();
  }
  float nm[4];
#pragma unroll
  for (int j = 0; j < 4; ++j) nm[j] = norms[rowbase + m0 + 4 * tx + j];
#pragma unroll
  for (int i = 0; i < 4; ++i)
#pragma unroll
    for (int j = 0; j < 4; ++j)
      g_D[(rowbase + q0 + 4 * ty + i) * N + m0 + 4 * tx + j] = nm[j] - 2.f * acc[i][j];
}

// ---------------- top-10: one wave per row ----------------
__global__ __launch_bounds__(256) void topk_kernel(int N) {
  int wid = (blockIdx.x * blockDim.x + threadIdx.x) >> 6;  // row in [0, BN)
  int lane = threadIdx.x & 63;
  if (wid >= BNTOT) return;
  int q = wid & (N - 1);
  const float* drow = g_D + (size_t)wid * N;
  // each lane owns a contiguous chunk of 32 candidates (N=2048 / 64 lanes)
  float dv[32];
  const int base = lane * 32;
#pragma unroll
  for (int j = 0; j < 32; j += 4) {
    float4 d4 = *(const float4*)(drow + base + j);
    dv[j] = d4.x; dv[j + 1] = d4.y; dv[j + 2] = d4.z; dv[j + 3] = d4.w;
  }
  if (q >= base && q < base + 32) dv[q - base] = FMAX;  // exclude self
  int* ob = g_ws_i + (size_t)wid * 10;
  for (int k = 0; k < 10; ++k) {
    // lane-local argmin (strict < keeps lowest index on ties)
    float bd = dv[0]; int bj = 0;
#pragma unroll
    for (int j = 1; j < 32; ++j)
      if (dv[j] < bd) { bd = dv[j]; bj = j; }
    float rd = bd; int rm = base + bj;
    // wave-wide lexicographic (d, m) min
#pragma unroll
    for (int off = 32; off > 0; off >>= 1) {
      float od = __shfl_down(rd, off, 64);
      int om = __shfl_down(rm, off, 64);
      if (od < rd || (od == rd && om < rm)) { rd = od; rm = om; }
    }
    rm = __shfl(rm, 0, 64);
    if (lane == 0) ob[k] = rm;
    if (rm >= base && rm < base + 32) dv[rm - base] = FMAX;  // retire winner
  }
}

// ---------------- G[z][BN][64] = X @ W_half[o_base:+64]^T ----------------
template <bool XDYN, int C>
__global__ __launch_bounds__(256) void gmat64_kernel(const void* xraw, size_t xoff,
                                                     int lda, const void* W,
                                                     int o_base, int BN) {
  const int isb = g_flag;
  constexpr int CC = (C <= 4) ? 4 : 64;
  constexpr int NCH = (C + CC - 1) / CC;
  __shared__ __align__(16) float at[CC][68];
  __shared__ __align__(16) float wt[CC][68];
  const int tid = threadIdx.x;
  const int ty = tid >> 4, tx = tid & 15;
  const int r0 = blockIdx.x * 64;
  const int z = blockIdx.z;
  float* Gz = g_ws_f + OFF_G + (size_t)z * BN * 64;
  float acc[4][4];
#pragma unroll
  for (int i = 0; i < 4; ++i)
#pragma unroll
    for (int j = 0; j < 4; ++j) acc[i][j] = 0.f;

  for (int ch = 0; ch < NCH; ++ch) {
    int c0 = ch * CC;
    for (int i = tid; i < 64 * CC; i += 256) {
      int r = i / CC, c = i % CC; int cg = c0 + c;
      size_t gi = (size_t)(r0 + r) * lda + cg;
      at[c][r] = (cg < C) ? (XDYN ? ldany(xraw, gi, isb) : g_ws_f[xoff + gi]) : 0.f;
    }
    for (int i = tid; i < 64 * CC; i += 256) {
      int r = i / CC, c = i % CC; int cg = c0 + c;
      size_t wi = (size_t)(o_base + r) * (2 * C) + (size_t)z * C + cg;
      wt[c][r] = (cg < C) ? ldany(W, wi, isb) : 0.f;
    }
    __syncthreads();
#pragma unroll 8
    for (int c = 0; c < CC; ++c) {
      const float4 a4 = *(const float4*)&at[c][4 * ty];
      const float4 w4 = *(const float4*)&wt[c][4 * tx];
      acc[0][0] += a4.x * w4.x; acc[0][1] += a4.x * w4.y; acc[0][2] += a4.x * w4.z; acc[0][3] += a4.x * w4.w;
      acc[1][0] += a4.y * w4.x; acc[1][1] += a4.y * w4.y; acc[1][2] += a4.y * w4.z; acc[1][3] += a4.y * w4.w;
      acc[2][0] += a4.z * w4.x; acc[2][1] += a4.z * w4.y; acc[2][2] += a4.z * w4.z; acc[2][3] += a4.z * w4.w;
      acc[3][0] += a4.w * w4.x; acc[3][1] += a4.w * w4.y; acc[3][2] += a4.w * w4.z; acc[3][3] += a4.w * w4.w;
    }
    __syncthreads();
  }
#pragma unroll
  for (int i = 0; i < 4; ++i)
#pragma unroll
    for (int j = 0; j < 4; ++j)
      Gz[(size_t)(r0 + 4 * ty + i) * 64 + 4 * tx + j] = acc[i][j];
}

// ---------------- edge-conv epilogue (64-out chunk) ----------------
__global__ void edge_epi64(const void* s, const void* t, int coff,
                           size_t outoff, int BN, int N) {
  const int isb = g_flag;
  int tid = threadIdx.x;
  int p = tid >> 6, o = tid & 63;
  int row = blockIdx.x * 4 + p;
  const float* G1 = g_ws_f + OFF_G;
  const float* G2 = G1 + (size_t)BN * 64;
  float* out = g_ws_f + outoff;
  int b = row / N;
  const int* id = g_ws_i + (size_t)row * 10;
  float g1n = G1[(size_t)row * 64 + o];
  float base = G2[(size_t)row * 64 + o] - g1n;
  float sv = ldany(s, coff + o, isb), tv = ldany(t, coff + o, isb);
  float mx = -FMAX;
#pragma unroll
  for (int k = 0; k < 10; ++k) {
    int m = id[k];
    m = (m < 0) ? 0 : ((m >= N) ? N - 1 : m);
    float h = sv * (G1[((size_t)b * N + m) * 64 + o] + base) + tv;
    h = (h >= 0.f) ? h : NEG * h;
    mx = fmaxf(mx, h);
  }
  out[(size_t)row * 512 + o] = mx;
}

// ---------------- W5 matmul + lrelu + partial max over n ----------------
__global__ __launch_bounds__(256) void w5max_kernel(const void* W5, const void* s5,
                                                    const void* t5, int N) {
  const int isb = g_flag;
  const float* cat = g_ws_f + OFF_CAT;
  float* part = g_ws_f + OFF_PART;
  __shared__ __align__(16) float at[64][68];
  __shared__ __align__(16) float wt[64][68];
  __shared__ __align__(16) float red[64][17];
  const int tid = threadIdx.x;
  const int ty = tid >> 4, tx = tid & 15;
  const int b = blockIdx.z;
  const int o0 = blockIdx.y * 64;
  const int n0 = blockIdx.x * 64;
  const size_t rowb = (size_t)b * N + n0;
  float acc[4][4];
#pragma unroll
  for (int i = 0; i < 4; ++i)
#pragma unroll
    for (int j = 0; j < 4; ++j) acc[i][j] = 0.f;

  for (int c0 = 0; c0 < 512; c0 += 64) {
    for (int i = tid; i < 64 * 64; i += 256) {
      int r = i >> 6, c = i & 63;
      at[c][r] = cat[(rowb + r) * 512 + c0 + c];
    }
    for (int i = tid; i < 64 * 64; i += 256) {
      int r = i >> 6, c = i & 63;
      wt[c][r] = ldany(W5, (size_t)(o0 + r) * 512 + c0 + c, isb);
    }
    __syncthreads();
#pragma unroll 8
    for (int c = 0; c < 64; ++c) {
      const float4 w4 = *(const float4*)&wt[c][4 * ty];
      const float4 a4 = *(const float4*)&at[c][4 * tx];
      acc[0][0] += w4.x * a4.x; acc[0][1] += w4.x * a4.y; acc[0][2] += w4.x * a4.z; acc[0][3] += w4.x * a4.w;
      acc[1][0] += w4.y * a4.x; acc[1][1] += w4.y * a4.y; acc[1][2] += w4.y * a4.z; acc[1][3] += w4.y * a4.w;
      acc[2][0] += w4.z * a4.x; acc[2][1] += w4.z * a4.y; acc[2][2] += w4.z * a4.z; acc[2][3] += w4.z * a4.w;
      acc[3][0] += w4.w * a4.x; acc[3][1] += w4.w * a4.y; acc[3][2] += w4.w * a4.z; acc[3][3] += w4.w * a4.w;
    }
    __syncthreads();
  }
#pragma unroll
  for (int i = 0; i < 4; ++i) {
    int o = o0 + 4 * ty + i;
    float sv = ldany(s5, o, isb), tv = ldany(t5, o, isb);
    float m = -FMAX;
#pragma unroll
    for (int j = 0; j < 4; ++j) {
      float h = sv * acc[i][j] + tv;
      h = (h >= 0.f) ? h : NEG * h;
      m = fmaxf(m, h);
    }
    red[4 * ty + i][tx] = m;
  }
  __syncthreads();
  if (tid < 64) {
    float m = -FMAX;
#pragma unroll
    for (int x = 0; x < 16; ++x) m = fmaxf(m, red[tid][x]);
    part[((size_t)b * 1024 + o0 + tid) * 32 + blockIdx.x] = m;
  }
}

__global__ void poolred_kernel() {
  const float* part = g_ws_f + OFF_PART;
  float* pooled = g_ws_f + OFF_POOLED;
  int i = blockIdx.x * blockDim.x + threadIdx.x;
  if (i >= 8 * 1024) return;
  const float* p = part + (size_t)i * 32;
  float m = -FMAX;
#pragma unroll
  for (int j = 0; j < 32; ++j) m = fmaxf(m, p[j]);
  pooled[i] = m;
}

// ---------------- FC: one wave per output ----------------
__global__ void fc_kernel(size_t inoff, const void* W, const void* bias,
                          const void* s, const void* t, size_t outoff, int has_out,
                          void* OUTB, int Bb, int IC, int OC, int act) {
  const int isb = g_flag;
  const float* IN = g_ws_f + inoff;
  int gw = (blockIdx.x * blockDim.x + threadIdx.x) >> 6;
  int lane = threadIdx.x & 63;
  if (gw >= Bb * OC) return;
  int b = gw / OC, o = gw % OC;
  const float* in = IN + (size_t)b * IC;
  float acc = 0.f;
  for (int c = lane; c < IC; c += 64) acc += in[c] * ldany(W, (size_t)o * IC + c, isb);
#pragma unroll
  for (int off = 32; off > 0; off >>= 1) acc += __shfl_down(acc, off, 64);
  if (lane == 0) {
    float h = acc;
    if (bias) h += ldany(bias, o, isb);
    if (s) h = h * ldany(s, o, isb) + ldany(t, o, isb);
    if (act) h = (h >= 0.f) ? h : NEG * h;
    if (has_out) g_ws_f[outoff + (size_t)b * OC + o] = h;
    if (OUTB) {
      if (isb) ((bf16*)OUTB)[(size_t)b * OC + o] = __float2bfloat16(h);
      else ((float*)OUTB)[(size_t)b * OC + o] = h;
    }
  }
}

extern "C" void kernel_launch(void* const* d_in, const int* in_sizes, int n_in,
                              void* d_out, int out_size, void* d_ws, size_t ws_size,
                              hipStream_t stream) {
  const int B = 8, N = 2048, BN = B * N;
  const void* points = d_in[0];
  const void *W1 = d_in[1], *s1 = d_in[2], *t1 = d_in[3];
  const void *W2 = d_in[4], *s2 = d_in[5], *t2 = d_in[6];
  const void *W3 = d_in[7], *s3 = d_in[8], *t3 = d_in[9];
  const void *W4 = d_in[10], *s4 = d_in[11], *t4 = d_in[12];
  const void *W5 = d_in[13], *s5 = d_in[14], *t5 = d_in[15];
  const void *Wf1 = d_in[16], *sf1 = d_in[17], *tf1 = d_in[18];
  const void *Wf2 = d_in[19], *bf2 = d_in[20], *sf2 = d_in[21], *tf2 = d_in[22];
  const void *Wf3 = d_in[23], *bf3 = d_in[24];

  probe_kernel<<<1, 1, 0, stream>>>(points);

  // ---- layer 1: points (C=3) -> cat[:, 0:64)
  norms_kernel<true><<<BN / 4, 256, 0, stream>>>(points, 0, 3, 3, BN);
  dist64_kernel<true, 3><<<dim3(N / 64, N / 64, B), 256, 0, stream>>>(points, 0, 3, N);
  topk_kernel<<<BN / 4, 256, 0, stream>>>(N);
  gmat64_kernel<true, 3><<<dim3(BN / 64, 1, 2), 256, 0, stream>>>(points, 0, 3, W1, 0, BN);
  edge_epi64<<<BN / 4, 256, 0, stream>>>(s1, t1, 0, OFF_CAT + 0, BN, N);
  // ---- layer 2: cat[:,0:64) (C=64) -> cat[:, 64:128)
  norms_kernel<false><<<BN / 4, 256, 0, stream>>>(nullptr, OFF_CAT + 0, 512, 64, BN);
  dist64_kernel<false, 64><<<dim3(N / 64, N / 64, B), 256, 0, stream>>>(nullptr, OFF_CAT + 0, 512, N);
  topk_kernel<<<BN / 4, 256, 0, stream>>>(N);
  gmat64_kernel<false, 64><<<dim3(BN / 64, 1, 2), 256, 0, stream>>>(nullptr, OFF_CAT + 0, 512, W2, 0, BN);
  edge_epi64<<<BN / 4, 256, 0, stream>>>(s2, t2, 0, OFF_CAT + 64, BN, N);
  // ---- layer 3: cat[:,64:128) (C=64) -> cat[:, 128:256)
  norms_kernel<false><<<BN / 4, 256, 0, stream>>>(nullptr, OFF_CAT + 64, 512, 64, BN);
  dist64_kernel<false, 64><<<dim3(N / 64, N / 64, B), 256, 0, stream>>>(nullptr, OFF_CAT + 64, 512, N);
  topk_kernel<<<BN / 4, 256, 0, stream>>>(N);
  for (int c = 0; c < 2; ++c) {
    gmat64_kernel<false, 64><<<dim3(BN / 64, 1, 2), 256, 0, stream>>>(nullptr, OFF_CAT + 64, 512, W3, c * 64, BN);
    edge_epi64<<<BN / 4, 256, 0, stream>>>(s3, t3, c * 64, OFF_CAT + 128 + c * 64, BN, N);
  }
  // ---- layer 4: cat[:,128:256) (C=128) -> cat[:, 256:512)
  norms_kernel<false><<<BN / 4, 256, 0, stream>>>(nullptr, OFF_CAT + 128, 512, 128, BN);
  dist64_kernel<false, 128><<<dim3(N / 64, N / 64, B), 256, 0, stream>>>(nullptr, OFF_CAT + 128, 512, N);
  topk_kernel<<<BN / 4, 256, 0, stream>>>(N);
  for (int c = 0; c < 4; ++c) {
    gmat64_kernel<false, 128><<<dim3(BN / 64, 1, 2), 256, 0, stream>>>(nullptr, OFF_CAT + 128, 512, W4, c * 64, BN);
    edge_epi64<<<BN / 4, 256, 0, stream>>>(s4, t4, c * 64, OFF_CAT + 256 + c * 64, BN, N);
  }
  // ---- W5 + global max pool
  w5max_kernel<<<dim3(32, 16, 8), 256, 0, stream>>>(W5, s5, t5, N);
  poolred_kernel<<<32, 256, 0, stream>>>();
  // ---- FC head
  fc_kernel<<<(8 * 512 * 64) / 256, 256, 0, stream>>>(OFF_POOLED, Wf1, nullptr, sf1, tf1, OFF_H1, 1, nullptr, 8, 1024, 512, 1);
  fc_kernel<<<(8 * 256 * 64) / 256, 256, 0, stream>>>(OFF_H1, Wf2, bf2, sf2, tf2, OFF_H2, 1, nullptr, 8, 512, 256, 1);
  fc_kernel<<<6, 256, 0, stream>>>(OFF_H2, Wf3, bf3, nullptr, nullptr, 0, 0, d_out, 8, 256, 3, 0);
}